// Round 1
// baseline (370.167 us; speedup 1.0000x reference)
//
#include <hip/hip_runtime.h>
#include <math.h>

#define NUM_CLASSES 80
#define MT 50            // max targets per image
#define ATOT 8400        // 80*80 + 40*40 + 20*20
#define CH 85            // 5 + NUM_CLASSES
#define BLOCK 256

__device__ __forceinline__ float softplusf(float x) {
    // stable softplus: max(x,0) + log1p(exp(-|x|))
    return fmaxf(x, 0.0f) + log1pf(expf(-fabsf(x)));
}

__global__ void zero_ws_kernel(float* ws, int n) {
    int i = blockIdx.x * blockDim.x + threadIdx.x;
    if (i < n) ws[i] = 0.0f;
}

__global__ __launch_bounds__(BLOCK) void yolox_stage1(
        const float* __restrict__ pred,   // [B, ATOT, CH]
        const float* __restrict__ tgt,    // [B, MT, 5]
        const int*   __restrict__ isz,    // scalar input_size
        float* __restrict__ acc) {        // [B, 4] : obj_sum, cls_sum, box_sum, num_pos
    const int b = blockIdx.x;
    const int a = blockIdx.y * BLOCK + threadIdx.x;

    __shared__ float st[MT * 5];
    for (int i = threadIdx.x; i < MT * 5; i += BLOCK)
        st[i] = tgt[b * MT * 5 + i];
    __syncthreads();

    const float fsize = (float)(*isz);

    float obj_sum = 0.f, cls_sum = 0.f, box_sum = 0.f, pos_cnt = 0.f;

    if (a < ATOT) {
        // anchor coords (strides 8/16/32, grids 80/40/20)
        int s, n, idx;
        if (a < 6400)      { s = 8;  n = 80; idx = a; }
        else if (a < 8000) { s = 16; n = 40; idx = a - 6400; }
        else               { s = 32; n = 20; idx = a - 8000; }
        const int yy = idx / n;
        const int xx = idx - yy * n;
        const float ax = (float)(xx * s + (s >> 1));
        const float ay = (float)(yy * s + (s >> 1));

        // argmin over targets (first-min tie-break like jnp.argmin)
        float best = INFINITY;
        int bestm = 0;
        for (int m = 0; m < MT; ++m) {
            const float c  = st[m * 5 + 0];
            const float gx = st[m * 5 + 1] * fsize;
            const float gy = st[m * 5 + 2] * fsize;
            const float dx = gx - ax, dy = gy - ay;
            float d2 = dx * dx + dy * dy;
            d2 = (c >= 0.0f) ? d2 : INFINITY;
            if (d2 < best) { best = d2; bestm = m; }
        }
        const bool pos = best < 4096.0f;  // 64^2
        const float posf = pos ? 1.0f : 0.0f;

        const float* p = pred + ((size_t)b * ATOT + (size_t)a) * CH;

        // objectness BCE (every anchor)
        const float ox = p[4];
        obj_sum = softplusf(ox) - ox * posf;

        if (pos) {
            pos_cnt = 1.0f;
            const int gcls = (int)st[bestm * 5 + 0];

            // class BCE vs one-hot: sum_c softplus(x_c) - x_{gcls}
            float cs = 0.f;
            #pragma unroll 4
            for (int c = 0; c < NUM_CLASSES; ++c) {
                const float x = p[5 + c];
                cs += softplusf(x);
                if (c == gcls) cs -= x;
            }
            cls_sum = cs;

            // IoU loss vs matched gt box
            const float gx = st[bestm * 5 + 1] * fsize;
            const float gy = st[bestm * 5 + 2] * fsize;
            const float gw = st[bestm * 5 + 3] * fsize;
            const float gh = st[bestm * 5 + 4] * fsize;

            const float pcx = p[0], pcy = p[1];
            const float pw = expf(p[2]), ph = expf(p[3]);
            const float p1x = pcx - pw * 0.5f, p2x = pcx + pw * 0.5f;
            const float p1y = pcy - ph * 0.5f, p2y = pcy + ph * 0.5f;
            const float t1x = gx - gw * 0.5f, t2x = gx + gw * 0.5f;
            const float t1y = gy - gh * 0.5f, t2y = gy + gh * 0.5f;
            const float iw = fminf(p2x, t2x) - fmaxf(p1x, t1x);
            const float ih = fminf(p2y, t2y) - fmaxf(p1y, t1y);
            const float inter = fmaxf(iw, 0.f) * fmaxf(ih, 0.f);
            const float pa = (p2x - p1x) * (p2y - p1y);
            const float ta = (t2x - t1x) * (t2y - t1y);
            const float uni = pa + ta - inter;
            box_sum = 1.0f - inter / (uni + 1e-6f);
        }
    }

    // block reduction: wave shuffle (64 lanes) then cross-wave via LDS
    float v0 = obj_sum, v1 = cls_sum, v2 = box_sum, v3 = pos_cnt;
    for (int off = 32; off > 0; off >>= 1) {
        v0 += __shfl_down(v0, off, 64);
        v1 += __shfl_down(v1, off, 64);
        v2 += __shfl_down(v2, off, 64);
        v3 += __shfl_down(v3, off, 64);
    }
    __shared__ float sred[BLOCK / 64][4];
    const int wave = threadIdx.x >> 6;
    const int lane = threadIdx.x & 63;
    if (lane == 0) {
        sred[wave][0] = v0; sred[wave][1] = v1;
        sred[wave][2] = v2; sred[wave][3] = v3;
    }
    __syncthreads();
    if (threadIdx.x == 0) {
        float t0 = 0.f, t1 = 0.f, t2 = 0.f, t3 = 0.f;
        for (int w = 0; w < BLOCK / 64; ++w) {
            t0 += sred[w][0]; t1 += sred[w][1];
            t2 += sred[w][2]; t3 += sred[w][3];
        }
        atomicAdd(&acc[b * 4 + 0], t0);
        atomicAdd(&acc[b * 4 + 1], t1);
        atomicAdd(&acc[b * 4 + 2], t2);
        atomicAdd(&acc[b * 4 + 3], t3);
    }
}

__global__ void yolox_stage2(const float* __restrict__ acc,
                             float* __restrict__ out, int B) {
    float obj = 0.f, cls = 0.f, box = 0.f, np = 0.f;
    for (int b = threadIdx.x; b < B; b += 64) {
        const float os = acc[b * 4 + 0];
        const float cs = acc[b * 4 + 1];
        const float bs = acc[b * 4 + 2];
        const float ps = acc[b * 4 + 3];
        obj += os / (float)ATOT;
        const float denom = fmaxf(ps, 1.0f);
        cls += (ps > 0.f) ? cs / (denom * (float)NUM_CLASSES) : 0.f;
        box += (ps > 0.f) ? bs / denom : 0.f;
        np  += ps;
    }
    for (int off = 32; off > 0; off >>= 1) {
        obj += __shfl_down(obj, off, 64);
        cls += __shfl_down(cls, off, 64);
        box += __shfl_down(box, off, 64);
        np  += __shfl_down(np,  off, 64);
    }
    if (threadIdx.x == 0) {
        out[0] = 5.0f * box + obj + cls;  // total
        out[1] = box;
        out[2] = obj;
        out[3] = cls;
        out[4] = np;
    }
}

extern "C" void kernel_launch(void* const* d_in, const int* in_sizes, int n_in,
                              void* d_out, int out_size, void* d_ws, size_t ws_size,
                              hipStream_t stream) {
    const float* pred = (const float*)d_in[0];
    const float* tgt  = (const float*)d_in[1];
    const int*   isz  = (const int*)d_in[2];
    float* out = (float*)d_out;
    float* acc = (float*)d_ws;

    const int B = in_sizes[1] / (MT * 5);

    zero_ws_kernel<<<(B * 4 + 255) / 256, 256, 0, stream>>>(acc, B * 4);

    dim3 grid(B, (ATOT + BLOCK - 1) / BLOCK);
    yolox_stage1<<<grid, BLOCK, 0, stream>>>(pred, tgt, isz, acc);

    yolox_stage2<<<1, 64, 0, stream>>>(acc, out, B);
}

// Round 3
// 270.620 us; speedup vs baseline: 1.3678x; 1.3678x over previous
//
#include <hip/hip_runtime.h>
#include <math.h>

#define NUM_CLASSES 80
#define MT 50            // max targets per image
#define ATOT 8400        // 80*80 + 40*40 + 20*20
#define CH 85            // 5 + NUM_CLASSES
#define BLOCK 256
#define NBY 33           // ceil(ATOT / BLOCK)

__device__ __forceinline__ float softplus_fast(float x) {
    // stable softplus via HW transcendentals: max(x,0) + log(1 + exp(-|x|))
    return fmaxf(x, 0.0f) + __logf(1.0f + __expf(-fabsf(x)));
}

__global__ __launch_bounds__(BLOCK) void yolox_stage1(
        const float* __restrict__ pred,   // [B, ATOT, CH]
        const float* __restrict__ tgt,    // [B, MT, 5]
        const int*   __restrict__ isz,    // scalar input_size
        float* __restrict__ acc) {        // [B, NBY, 4]
    const int b  = blockIdx.x;
    const int by = blockIdx.y;
    const int a  = by * BLOCK + threadIdx.x;

    __shared__ float2 sxy[MT];   // gx,gy (premultiplied by fsize)
    __shared__ float2 swh[MT];   // gw,gh (premultiplied)
    __shared__ float  scls[MT];
    __shared__ int    snv;

    if (threadIdx.x == 0) {
        const float fsize = (float)(*isz);
        const float* tb = tgt + (size_t)b * MT * 5;
        int nv = 0;
        for (int m = 0; m < MT; ++m) {
            const float c = tb[m * 5 + 0];
            if (c >= 0.0f) {
                sxy[nv]  = make_float2(tb[m * 5 + 1] * fsize, tb[m * 5 + 2] * fsize);
                swh[nv]  = make_float2(tb[m * 5 + 3] * fsize, tb[m * 5 + 4] * fsize);
                scls[nv] = c;
                ++nv;
            }
        }
        snv = nv;
    }
    __syncthreads();
    const int nv = snv;

    float obj_sum = 0.f, cls_sum = 0.f, box_sum = 0.f, pos_cnt = 0.f;

    if (a < ATOT) {
        // anchor coords (strides 8/16/32, grids 80/40/20)
        int s, n, idx;
        if (a < 6400)      { s = 8;  n = 80; idx = a; }
        else if (a < 8000) { s = 16; n = 40; idx = a - 6400; }
        else               { s = 32; n = 20; idx = a - 8000; }
        const int yy = idx / n;
        const int xx = idx - yy * n;
        const float ax = (float)(xx * s + (s >> 1));
        const float ay = (float)(yy * s + (s >> 1));

        // argmin over compacted valid targets (order-preserving, strict <)
        float best = INFINITY;
        int bestm = 0;
        for (int m = 0; m < nv; ++m) {
            const float2 g = sxy[m];
            const float dx = g.x - ax, dy = g.y - ay;
            const float d2 = dx * dx + dy * dy;
            if (d2 < best) { best = d2; bestm = m; }
        }
        const bool pos = best < 4096.0f;  // 64^2
        const float posf = pos ? 1.0f : 0.0f;

        const float* p = pred + ((size_t)b * ATOT + (size_t)a) * CH;

        // objectness BCE (every anchor)
        const float ox = p[4];
        obj_sum = softplus_fast(ox) - ox * posf;

        if (pos) {
            pos_cnt = 1.0f;
            const int gcls = (int)scls[bestm];

            // class BCE vs one-hot: sum_c softplus(x_c) - x_{gcls}
            float cs0 = 0.f, cs1 = 0.f;
            #pragma unroll 8
            for (int c = 0; c < NUM_CLASSES; c += 2) {
                cs0 += softplus_fast(p[5 + c]);
                cs1 += softplus_fast(p[6 + c]);
            }
            cls_sum = cs0 + cs1 - p[5 + gcls];

            // IoU loss vs matched gt box
            const float2 g  = sxy[bestm];
            const float2 wh = swh[bestm];

            const float pcx = p[0], pcy = p[1];
            const float pw = __expf(p[2]), ph = __expf(p[3]);
            const float p1x = pcx - pw * 0.5f, p2x = pcx + pw * 0.5f;
            const float p1y = pcy - ph * 0.5f, p2y = pcy + ph * 0.5f;
            const float t1x = g.x - wh.x * 0.5f, t2x = g.x + wh.x * 0.5f;
            const float t1y = g.y - wh.y * 0.5f, t2y = g.y + wh.y * 0.5f;
            const float iw = fminf(p2x, t2x) - fmaxf(p1x, t1x);
            const float ih = fminf(p2y, t2y) - fmaxf(p1y, t1y);
            const float inter = fmaxf(iw, 0.f) * fmaxf(ih, 0.f);
            const float pa = (p2x - p1x) * (p2y - p1y);
            const float ta = (t2x - t1x) * (t2y - t1y);
            const float uni = pa + ta - inter;
            box_sum = 1.0f - inter / (uni + 1e-6f);
        }
    }

    // block reduction: wave shuffle then cross-wave via LDS
    float v0 = obj_sum, v1 = cls_sum, v2 = box_sum, v3 = pos_cnt;
    for (int off = 32; off > 0; off >>= 1) {
        v0 += __shfl_down(v0, off, 64);
        v1 += __shfl_down(v1, off, 64);
        v2 += __shfl_down(v2, off, 64);
        v3 += __shfl_down(v3, off, 64);
    }
    __shared__ float sred[BLOCK / 64][4];
    const int wave = threadIdx.x >> 6;
    const int lane = threadIdx.x & 63;
    if (lane == 0) {
        sred[wave][0] = v0; sred[wave][1] = v1;
        sred[wave][2] = v2; sred[wave][3] = v3;
    }
    __syncthreads();
    if (threadIdx.x == 0) {
        float t0 = 0.f, t1 = 0.f, t2 = 0.f, t3 = 0.f;
        #pragma unroll
        for (int w = 0; w < BLOCK / 64; ++w) {
            t0 += sred[w][0]; t1 += sred[w][1];
            t2 += sred[w][2]; t3 += sred[w][3];
        }
        float* slot = acc + ((size_t)b * NBY + by) * 4;
        slot[0] = t0; slot[1] = t1; slot[2] = t2; slot[3] = t3;
    }
}

__global__ void yolox_stage2(const float* __restrict__ acc,
                             float* __restrict__ out, int B) {
    // one wave: lane b owns image b (B <= 64 here; loop handles larger B)
    float obj = 0.f, cls = 0.f, box = 0.f, np = 0.f;
    for (int b = threadIdx.x; b < B; b += 64) {
        float os = 0.f, cs = 0.f, bs = 0.f, ps = 0.f;
        const float* s = acc + (size_t)b * NBY * 4;
        for (int j = 0; j < NBY; ++j) {
            os += s[j * 4 + 0];
            cs += s[j * 4 + 1];
            bs += s[j * 4 + 2];
            ps += s[j * 4 + 3];
        }
        obj += os * (1.0f / (float)ATOT);
        const float denom = fmaxf(ps, 1.0f);
        cls += (ps > 0.f) ? cs / (denom * (float)NUM_CLASSES) : 0.f;
        box += (ps > 0.f) ? bs / denom : 0.f;
        np  += ps;
    }
    for (int off = 32; off > 0; off >>= 1) {
        obj += __shfl_down(obj, off, 64);
        cls += __shfl_down(cls, off, 64);
        box += __shfl_down(box, off, 64);
        np  += __shfl_down(np,  off, 64);
    }
    if (threadIdx.x == 0) {
        out[0] = 5.0f * box + obj + cls;  // total
        out[1] = box;
        out[2] = obj;
        out[3] = cls;
        out[4] = np;
    }
}

extern "C" void kernel_launch(void* const* d_in, const int* in_sizes, int n_in,
                              void* d_out, int out_size, void* d_ws, size_t ws_size,
                              hipStream_t stream) {
    const float* pred = (const float*)d_in[0];
    const float* tgt  = (const float*)d_in[1];
    const int*   isz  = (const int*)d_in[2];
    float* out = (float*)d_out;
    float* acc = (float*)d_ws;   // B*NBY*4 floats

    const int B = in_sizes[1] / (MT * 5);

    dim3 grid(B, NBY);
    yolox_stage1<<<grid, BLOCK, 0, stream>>>(pred, tgt, isz, acc);
    yolox_stage2<<<1, 64, 0, stream>>>(acc, out, B);
}